// Round 5
// baseline (196.650 us; speedup 1.0000x reference)
//
#include <hip/hip_runtime.h>
#include <hip/hip_bf16.h>

// CrossAttention: B=4, C=256, H=W=64 -> N=M=4096, RC=32
// v5: attn software-pipelined with lag-1 P (PV(i-1) overlaps S/exp(i));
//     V double-buffer staged at iter i for use at i+1; P ping-pong x 2 tiles.
//     proj kernels: 1 tile/wave (2x blocks) to cut block-lifetime latency.
//     combine: vectorized Lp loads.

#define B_ 4
#define C_ 256
#define N_ 4096
#define M_ 4096
#define SCALE_ 0.17677669529663687f  // 1/sqrt(32)

typedef __bf16 bf16x8 __attribute__((ext_vector_type(8)));
typedef float f32x4 __attribute__((ext_vector_type(4)));

#define AS1 __attribute__((address_space(1)))
#define AS3 __attribute__((address_space(3)))

static __device__ __forceinline__ unsigned short f2bf(float f) {
    unsigned int u = __float_as_uint(f);
    return (unsigned short)((u + 0x7fffu + ((u >> 16) & 1u)) >> 16);
}
static __device__ __forceinline__ unsigned bfpk(float a, float b) {
    return (unsigned)f2bf(a) | ((unsigned)f2bf(b) << 16);
}
static __device__ __forceinline__ float fp8d(unsigned v) {  // e4m3fn decode
    unsigned e = (v >> 3) & 15, m = v & 7;
    float f = e ? __uint_as_float(((e + 120u) << 23) | (m << 20))
                : (float)m * 0x1p-9f;
    return (v & 0x80u) ? -f : f;
}
static __device__ __forceinline__ void gload_lds16(const void* g, void* l) {
    __builtin_amdgcn_global_load_lds((const AS1 unsigned int*)g,
                                     (AS3 unsigned int*)l, 16, 0, 0);
}

// ---------------------------------------------------------------------------
// Transpose: in[b][c][p] fp32 -> out[b][p][c] bf16.  grid 2048 x 256.
// ---------------------------------------------------------------------------
__global__ __launch_bounds__(256) void transpose_bf(
        const float* __restrict__ x, const float* __restrict__ ctx,
        unsigned short* __restrict__ xT, unsigned short* __restrict__ ctxT) {
    __shared__ unsigned short T[64][68];
    int bid = blockIdx.x;
    int tens = bid >> 10;
    int r = bid & 1023;
    int b = r >> 8, rr = r & 255;
    int pt = rr >> 2, ct = rr & 3;
    const float* __restrict__ in = (tens ? ctx : x) + (size_t)b * C_ * N_;
    unsigned short* __restrict__ outp = (tens ? ctxT : xT) + (size_t)b * N_ * C_;
    int t = threadIdx.x;

    {
        int p = t & 63, cg = t >> 6;
        const float* src = in + (size_t)(ct * 64 + cg * 16) * N_ + pt * 64 + p;
        float v[16];
#pragma unroll
        for (int k = 0; k < 16; k++) v[k] = src[(size_t)k * N_];
#pragma unroll
        for (int k = 0; k < 16; k += 2)
            *(unsigned*)&T[p][cg * 16 + k] = bfpk(v[k], v[k + 1]);
    }
    __syncthreads();
    {
        int p2 = t >> 2, cq = t & 3;
        uint2 a = *(const uint2*)&T[p2][cq * 16];
        uint2 bq_ = *(const uint2*)&T[p2][cq * 16 + 4];
        uint2 c = *(const uint2*)&T[p2][cq * 16 + 8];
        uint2 d = *(const uint2*)&T[p2][cq * 16 + 12];
        size_t ob = (size_t)(pt * 64 + p2) * C_ + ct * 64 + cq * 16;
        uint4 s0 = {a.x, a.y, bq_.x, bq_.y};
        uint4 s1 = {c.x, c.y, d.x, d.y};
        *(uint4*)(outp + ob) = s0;
        *(uint4*)(outp + ob + 8) = s1;
    }
}

// ---------------------------------------------------------------------------
// Q/K projection GEMM. grid 512 x 256 thr. bid>>8: 0=Q(from xT),1=K(from ctxT).
// One ptile per wave (2x blocks vs v4 to cut block-lifetime serialization).
// ---------------------------------------------------------------------------
__global__ __launch_bounds__(256) void proj_qk(
        const unsigned short* __restrict__ xT, const unsigned short* __restrict__ ctxT,
        const float* __restrict__ Wq, const float* __restrict__ bq,
        const float* __restrict__ Wk, const float* __restrict__ bk,
        unsigned short* __restrict__ Qf, unsigned short* __restrict__ Kf) {
    __shared__ unsigned short Pl[4][16 * 40];
    int bid = blockIdx.x;
    int tens = bid >> 8;
    int blk = bid & 255;
    int wave = threadIdx.x >> 6, lane = threadIdx.x & 63;
    int q = lane >> 4, low = lane & 15;
    const unsigned short* __restrict__ in = tens ? ctxT : xT;
    const float* __restrict__ W = tens ? Wk : Wq;
    const float* __restrict__ bias = tens ? bk : bq;
    unsigned short* __restrict__ dst = tens ? Kf : Qf;

    bf16x8 af[2][8];
#pragma unroll
    for (int rt = 0; rt < 2; rt++)
#pragma unroll
        for (int ch = 0; ch < 8; ch++) {
            const float* wp = W + (size_t)(rt * 16 + low) * C_ + ch * 32 + q * 8;
            float4 w0 = *(const float4*)wp;
            float4 w1 = *(const float4*)(wp + 4);
            uint4 pk = {bfpk(w0.x, w0.y), bfpk(w0.z, w0.w),
                        bfpk(w1.x, w1.y), bfpk(w1.z, w1.w)};
            af[rt][ch] = __builtin_bit_cast(bf16x8, pk);
        }
    float bb[2][4];
#pragma unroll
    for (int rt = 0; rt < 2; rt++)
#pragma unroll
        for (int rg = 0; rg < 4; rg++) bb[rt][rg] = bias[rt * 16 + q * 4 + rg];

    unsigned short* Pw = &Pl[wave][0];
    const f32x4 zero = {0.f, 0.f, 0.f, 0.f};

    int pt = blk * 4 + wave;              // 0..1023
    int b = pt >> 8, ptl = pt & 255;
    const unsigned short* src = in + ((size_t)b * N_ + ptl * 16 + low) * C_;
    f32x4 acc[2] = {zero, zero};
#pragma unroll
    for (int ch = 0; ch < 8; ch++) {
        uint4 bv = *(const uint4*)(src + ch * 32 + q * 8);
        bf16x8 bfr = __builtin_bit_cast(bf16x8, bv);
        acc[0] = __builtin_amdgcn_mfma_f32_16x16x32_bf16(af[0][ch], bfr, acc[0], 0, 0, 0);
        acc[1] = __builtin_amdgcn_mfma_f32_16x16x32_bf16(af[1][ch], bfr, acc[1], 0, 0, 0);
    }
#pragma unroll
    for (int rt = 0; rt < 2; rt++) {
        uint2 pk = {bfpk(acc[rt][0] + bb[rt][0], acc[rt][1] + bb[rt][1]),
                    bfpk(acc[rt][2] + bb[rt][2], acc[rt][3] + bb[rt][3])};
        *(uint2*)(Pw + low * 40 + rt * 16 + q * 4) = pk;
    }
    uint4 frag = *(const uint4*)(Pw + low * 40 + q * 8);
    ((uint4*)dst)[(size_t)(b * 256 + ptl) * 64 + lane] = frag;
}

// ---------------------------------------------------------------------------
// V projection GEMM. grid 1024 x 256 thr. bid: mg(7)|dg(3). One mc per wave.
// ---------------------------------------------------------------------------
__global__ __launch_bounds__(256) void proj_v(
        const unsigned short* __restrict__ ctxT, const float* __restrict__ Wv,
        const float* __restrict__ bv, unsigned char* __restrict__ Vf) {
    __shared__ unsigned char Vl[4][32 * 40];
    int bid = blockIdx.x;
    int dg = bid & 7;
    int mg = bid >> 3;          // 0..127
    int wave = threadIdx.x >> 6, lane = threadIdx.x & 63;
    int q = lane >> 4, low = lane & 15;

    bf16x8 bf[2][8];
#pragma unroll
    for (int dt = 0; dt < 2; dt++)
#pragma unroll
        for (int ch = 0; ch < 8; ch++) {
            const float* wp = Wv + (size_t)(dg * 32 + dt * 16 + low) * C_ + ch * 32 + q * 8;
            float4 w0 = *(const float4*)wp;
            float4 w1 = *(const float4*)(wp + 4);
            uint4 pk = {bfpk(w0.x, w0.y), bfpk(w0.z, w0.w),
                        bfpk(w1.x, w1.y), bfpk(w1.z, w1.w)};
            bf[dt][ch] = __builtin_bit_cast(bf16x8, pk);
        }
    float bvv[2];
    bvv[0] = bv[dg * 32 + low];
    bvv[1] = bv[dg * 32 + 16 + low];

    unsigned char* Vw = &Vl[wave][0];
    const f32x4 zero = {0.f, 0.f, 0.f, 0.f};

    int mc = mg * 4 + wave;               // 0..511
    int b = mc >> 7, mcl = mc & 127;
    f32x4 acc[2][2];
#pragma unroll
    for (int mt = 0; mt < 2; mt++) {
        acc[mt][0] = zero; acc[mt][1] = zero;
        const unsigned short* src =
            ctxT + ((size_t)b * M_ + mcl * 32 + mt * 16 + low) * C_;
#pragma unroll
        for (int ch = 0; ch < 8; ch++) {
            uint4 av = *(const uint4*)(src + ch * 32 + q * 8);
            bf16x8 afr = __builtin_bit_cast(bf16x8, av);
            acc[mt][0] = __builtin_amdgcn_mfma_f32_16x16x32_bf16(afr, bf[0][ch], acc[mt][0], 0, 0, 0);
            acc[mt][1] = __builtin_amdgcn_mfma_f32_16x16x32_bf16(afr, bf[1][ch], acc[mt][1], 0, 0, 0);
        }
    }
#pragma unroll
    for (int mt = 0; mt < 2; mt++)
#pragma unroll
        for (int dt = 0; dt < 2; dt++) {
            float v0 = acc[mt][dt][0] + bvv[dt], v1 = acc[mt][dt][1] + bvv[dt];
            float v2 = acc[mt][dt][2] + bvv[dt], v3 = acc[mt][dt][3] + bvv[dt];
            unsigned w = __builtin_amdgcn_cvt_pk_fp8_f32(v0, v1, 0, false);
            w = __builtin_amdgcn_cvt_pk_fp8_f32(v2, v3, w, true);
            *(unsigned*)(Vw + (dt * 16 + low) * 40 + mt * 16 + q * 4) = w;
        }
#pragma unroll
    for (int dt = 0; dt < 2; dt++) {
        uint2 frag = *(const uint2*)(Vw + (dt * 16 + low) * 40 + q * 8);
        ((uint2*)Vf)[(((size_t)b * 128 + mcl) * 16 + dg * 2 + dt) * 64 + lane] = frag;
    }
}

// ---------------------------------------------------------------------------
// Flash attention, split-m, software-pipelined (lag-1 P). grid 512, 256 thr.
// iter i: barrier; DMA V(i)->buf[i&1]; S(i); PV(i-1) from buf[(i-1)&1] and
// Pb[(i-1)&1]; exp/P(i)->Pb[i&1]. Final PV(15) after a closing barrier.
// ---------------------------------------------------------------------------
__global__ __launch_bounds__(256, 2) void attn(
        const unsigned short* __restrict__ Qf, const unsigned short* __restrict__ Kf,
        const unsigned char* __restrict__ Vf, unsigned char* __restrict__ Op,
        float* __restrict__ Lp) {
    __shared__ __align__(16) unsigned char vbuf[2][16384];       // 32 KB
    __shared__ __align__(16) unsigned char Plds[2][4][2][16 * 72]; // 18.4 KB

    int v = blockIdx.x & 15;
    int b = v >> 2, chunk = v & 3;
    int ntg = blockIdx.x >> 4;              // 0..31
    int wave = threadIdx.x >> 6, lane = threadIdx.x & 63;
    int quad = lane >> 4, col = lane & 15;
    int nt0 = ntg * 8 + wave * 2;

    const uint4* Qp = (const uint4*)Qf;
    const uint4* Kp = (const uint4*)Kf + (size_t)b * 256 * 64;
    const unsigned char* Vp = Vf + (size_t)b * 1048576;

    bf16x8 qa[2];
    qa[0] = __builtin_bit_cast(bf16x8, Qp[(size_t)(b * 256 + nt0 + 0) * 64 + lane]);
    qa[1] = __builtin_bit_cast(bf16x8, Qp[(size_t)(b * 256 + nt0 + 1) * 64 + lane]);

    f32x4 acc[2][16];
#pragma unroll
    for (int j = 0; j < 2; j++)
#pragma unroll
        for (int dt = 0; dt < 16; dt++) acc[j][dt] = (f32x4){0.f, 0.f, 0.f, 0.f};
    float lacc[2][4] = {{0.f, 0.f, 0.f, 0.f}, {0.f, 0.f, 0.f, 0.f}};

    const f32x4 zero = {0.f, 0.f, 0.f, 0.f};
    int ms0 = chunk * 16;

    uint4 kv[4];
#pragma unroll
    for (int u = 0; u < 4; u++)
        kv[u] = Kp[(size_t)(ms0 * 4 + u) * 64 + lane];

    for (int i = 0; i < 16; i++) {
        int ms = ms0 + i;
        __syncthreads();   // V(i-1) staged+drained; PV(i-2) complete everywhere

        // ---- stage V(i) into buf[i&1] (used at iter i+1) ----
#pragma unroll
        for (int ii = 0; ii < 4; ii++) {
            int ck = wave * 4 + ii;
            gload_lds16(Vp + (size_t)ms * 16384 + ck * 1024 + lane * 16,
                        &vbuf[i & 1][0] + ck * 1024 + lane * 16);
        }

        // ---- S(i) = Q K^T (8 MFMAs) ----
        f32x4 s[2][4];
#pragma unroll
        for (int j = 0; j < 2; j++)
#pragma unroll
            for (int u = 0; u < 4; u++)
                s[j][u] = __builtin_amdgcn_mfma_f32_16x16x32_bf16(
                    qa[j], __builtin_bit_cast(bf16x8, kv[u]), zero, 0, 0, 0);

        // ---- prefetch K(i+1) ----
        if (i < 15) {
#pragma unroll
            for (int u = 0; u < 4; u++)
                kv[u] = Kp[(size_t)((ms + 1) * 4 + u) * 64 + lane];
        }

        // ---- PV(i-1): 64 MFMAs, P and V one iteration old ----
        if (i > 0) {
            const unsigned char* Pr = &Plds[(i - 1) & 1][wave][0][0];
            const unsigned char* vb = &vbuf[(i - 1) & 1][0];
#pragma unroll
            for (int j = 0; j < 2; j++) {
                unsigned long long pa0 = *(const unsigned long long*)(Pr + j * 1152 + col * 72 + quad * 8);
                unsigned long long pa1 = *(const unsigned long long*)(Pr + j * 1152 + col * 72 + 32 + quad * 8);
#pragma unroll
                for (int dt = 0; dt < 16; dt++) {
                    long v0 = *(const long*)(vb + (size_t)dt * 512 + lane * 8);
                    long v1 = *(const long*)(vb + (size_t)(16 + dt) * 512 + lane * 8);
                    acc[j][dt] = __builtin_amdgcn_mfma_f32_16x16x32_fp8_fp8(
                        (long)pa0, v0, acc[j][dt], 0, 0, 0);
                    acc[j][dt] = __builtin_amdgcn_mfma_f32_16x16x32_fp8_fp8(
                        (long)pa1, v1, acc[j][dt], 0, 0, 0);
                }
            }
        }

        // ---- exp/P(i) -> Plds[i&1] (off the MFMA critical path) ----
        unsigned char* Pw = &Plds[i & 1][wave][0][0];
#pragma unroll
        for (int j = 0; j < 2; j++) {
#pragma unroll
            for (int u = 0; u < 4; u++) {
#pragma unroll
                for (int r = 0; r < 4; r++) {
                    float pe = __expf(s[j][u][r] * SCALE_);
                    lacc[j][r] += pe;
                    unsigned w8 = __builtin_amdgcn_cvt_pk_fp8_f32(pe, pe, 0, false);
                    Pw[j * 1152 + (quad * 4 + r) * 72 + u * 16 + col] = (unsigned char)w8;
                }
            }
        }
    }

    // ---- final PV(15) ----
    __syncthreads();
    {
        const unsigned char* Pr = &Plds[1][wave][0][0];
        const unsigned char* vb = &vbuf[1][0];
#pragma unroll
        for (int j = 0; j < 2; j++) {
            unsigned long long pa0 = *(const unsigned long long*)(Pr + j * 1152 + col * 72 + quad * 8);
            unsigned long long pa1 = *(const unsigned long long*)(Pr + j * 1152 + col * 72 + 32 + quad * 8);
#pragma unroll
            for (int dt = 0; dt < 16; dt++) {
                long v0 = *(const long*)(vb + (size_t)dt * 512 + lane * 8);
                long v1 = *(const long*)(vb + (size_t)(16 + dt) * 512 + lane * 8);
                acc[j][dt] = __builtin_amdgcn_mfma_f32_16x16x32_fp8_fp8(
                    (long)pa0, v0, acc[j][dt], 0, 0, 0);
                acc[j][dt] = __builtin_amdgcn_mfma_f32_16x16x32_fp8_fp8(
                    (long)pa1, v1, acc[j][dt], 0, 0, 0);
            }
        }
    }

#pragma unroll
    for (int off = 1; off <= 8; off <<= 1) {
#pragma unroll
        for (int j = 0; j < 2; j++)
#pragma unroll
            for (int r = 0; r < 4; r++)
                lacc[j][r] += __shfl_xor(lacc[j][r], off, 64);
    }
#pragma unroll
    for (int j = 0; j < 2; j++) {
        int tileg = b * 256 + nt0 + j;
        if (col == 0) {
#pragma unroll
            for (int r = 0; r < 4; r++)
                Lp[((size_t)tileg * 4 + chunk) * 16 + quad * 4 + r] = lacc[j][r];
        }
#pragma unroll
        for (int dt = 0; dt < 16; dt++) {
            int d = dt * 16 + col;
            size_t sb = ((size_t)(b * 4 + chunk) * C_ + d) * N_ + (nt0 + j) * 16 + quad * 4;
            unsigned w = __builtin_amdgcn_cvt_pk_fp8_f32(acc[j][dt][0], acc[j][dt][1], 0, false);
            w = __builtin_amdgcn_cvt_pk_fp8_f32(acc[j][dt][2], acc[j][dt][3], w, true);
            *(unsigned*)(Op + sb) = w;
        }
    }
}

// ---------------------------------------------------------------------------
// Combine: out = gamma * (sum_c O_c) / (sum_c l_c) + x. HBM-bound.
// ---------------------------------------------------------------------------
__global__ __launch_bounds__(256) void combine(
        const unsigned char* __restrict__ Op, const float* __restrict__ Lp,
        const float* __restrict__ x, const float* __restrict__ gamma,
        float* __restrict__ out) {
    int idx = blockIdx.x * 256 + threadIdx.x;
    int n4 = idx & 1023;
    int d = (idx >> 10) & 255;
    int b = idx >> 18;
    int n = n4 * 4;
    int tile = b * 256 + (n >> 4);
    int row0 = n & 15;

    float o[4] = {0.f, 0.f, 0.f, 0.f};
    f32x4 l = {0.f, 0.f, 0.f, 0.f};
#pragma unroll
    for (int c = 0; c < 4; c++) {
        size_t sb = ((size_t)(b * 4 + c) * C_ + d) * N_ + n;
        unsigned pv = *(const unsigned*)(Op + sb);
        o[0] += fp8d(pv & 0xffu);
        o[1] += fp8d((pv >> 8) & 0xffu);
        o[2] += fp8d((pv >> 16) & 0xffu);
        o[3] += fp8d(pv >> 24);
        f32x4 lv = *(const f32x4*)&Lp[((size_t)tile * 4 + c) * 16 + row0];
        l += lv;
    }
    float g = gamma[0];
    size_t ob = ((size_t)b * C_ + d) * N_ + n;
    f32x4 xv = *(const f32x4*)(x + ob);
    f32x4 res;
#pragma unroll
    for (int r = 0; r < 4; r++) res[r] = g * o[r] / l[r] + xv[r];
    *(f32x4*)(out + ob) = res;
}

// ---------------------------------------------------------------------------
extern "C" void kernel_launch(void* const* d_in, const int* in_sizes, int n_in,
                              void* d_out, int out_size, void* d_ws, size_t ws_size,
                              hipStream_t stream) {
    const float* x     = (const float*)d_in[0];
    const float* ctx   = (const float*)d_in[1];
    const float* Wq    = (const float*)d_in[2];
    const float* bq    = (const float*)d_in[3];
    const float* Wk    = (const float*)d_in[4];
    const float* bk    = (const float*)d_in[5];
    const float* Wv    = (const float*)d_in[6];
    const float* bv    = (const float*)d_in[7];
    const float* gamma = (const float*)d_in[8];
    float* out = (float*)d_out;

    // ws: xT 8.4M | ctxT 8.4M | Qf 1M | Kf 1M | Vf 4.2M | Op 16.8M | Lp 1M
    unsigned short* xT   = (unsigned short*)d_ws;
    unsigned short* ctxT = xT + (size_t)B_ * N_ * C_;
    unsigned short* Qf   = ctxT + (size_t)B_ * M_ * C_;
    unsigned short* Kf   = Qf + (size_t)B_ * N_ * 32;
    unsigned char*  Vf   = (unsigned char*)(Kf + (size_t)B_ * M_ * 32);
    unsigned char*  Op   = Vf + (size_t)B_ * M_ * C_;
    float*          Lp   = (float*)(Op + (size_t)B_ * 4 * C_ * N_);

    transpose_bf<<<2048, 256, 0, stream>>>(x, ctx, xT, ctxT);
    proj_qk<<<512, 256, 0, stream>>>(xT, ctxT, Wq, bq, Wk, bk, Qf, Kf);
    proj_v<<<1024, 256, 0, stream>>>(ctxT, Wv, bv, Vf);
    attn<<<512, 256, 0, stream>>>(Qf, Kf, Vf, Op, Lp);
    combine<<<4096, 256, 0, stream>>>(Op, Lp, x, gamma, out);
}

// Round 6
// 176.470 us; speedup vs baseline: 1.1144x; 1.1144x over previous
//
#include <hip/hip_runtime.h>
#include <hip/hip_bf16.h>

// CrossAttention: B=4, C=256, H=W=64 -> N=M=4096, RC=32
// v6: prep (W -> bf16 MFMA fragments) + fused transpose/proj (no xT/ctxT
//     round-trip) + attn (1 q-tile/wave, split-m 8, 4 waves/SIMD) + combine.

#define B_ 4
#define C_ 256
#define N_ 4096
#define M_ 4096
#define SCALE_ 0.17677669529663687f  // 1/sqrt(32)

typedef __bf16 bf16x8 __attribute__((ext_vector_type(8)));
typedef float f32x4 __attribute__((ext_vector_type(4)));

#define AS1 __attribute__((address_space(1)))
#define AS3 __attribute__((address_space(3)))

static __device__ __forceinline__ unsigned short f2bf(float f) {
    unsigned int u = __float_as_uint(f);
    return (unsigned short)((u + 0x7fffu + ((u >> 16) & 1u)) >> 16);
}
static __device__ __forceinline__ unsigned bfpk(float a, float b) {
    return (unsigned)f2bf(a) | ((unsigned)f2bf(b) << 16);
}
static __device__ __forceinline__ float fp8d(unsigned v) {  // e4m3fn decode
    unsigned e = (v >> 3) & 15, m = v & 7;
    float f = e ? __uint_as_float(((e + 120u) << 23) | (m << 20))
                : (float)m * 0x1p-9f;
    return (v & 0x80u) ? -f : f;
}
static __device__ __forceinline__ void gload_lds16(const void* g, void* l) {
    __builtin_amdgcn_global_load_lds((const AS1 unsigned int*)g,
                                     (AS3 unsigned int*)l, 16, 0, 0);
}

// ---------------------------------------------------------------------------
// prep: weights -> bf16 MFMA fragment order. Wv: 128 frags (dt 16 x ch 8),
// Wq/Wk: 16 frags (rt 2 x ch 8). One uint4 per (frag, lane).
// grid 40 x 256.
// ---------------------------------------------------------------------------
__global__ __launch_bounds__(256) void prep(
        const float* __restrict__ Wq, const float* __restrict__ Wk,
        const float* __restrict__ Wv, uint4* __restrict__ Wqf,
        uint4* __restrict__ Wkf, uint4* __restrict__ Wvf) {
    int bid = blockIdx.x, t = threadIdx.x;
    const float* W;
    uint4* dst;
    int frag;
    if (bid < 32)      { W = Wv; dst = Wvf; frag = (bid * 256 + t) >> 6; }
    else if (bid < 36) { W = Wq; dst = Wqf; frag = ((bid - 32) * 256 + t) >> 6; }
    else               { W = Wk; dst = Wkf; frag = ((bid - 36) * 256 + t) >> 6; }
    int lane = t & 63, low = lane & 15, q = lane >> 4;
    int fch = frag & 7, fr = frag >> 3;
    const float* wp = W + (size_t)(fr * 16 + low) * C_ + fch * 32 + q * 8;
    float4 w0 = *(const float4*)wp;
    float4 w1 = *(const float4*)(wp + 4);
    uint4 pk = {bfpk(w0.x, w0.y), bfpk(w0.z, w0.w),
                bfpk(w1.x, w1.y), bfpk(w1.z, w1.w)};
    dst[(size_t)frag * 64 + lane] = pk;
}

// ---------------------------------------------------------------------------
// Fused transpose + projections. grid 512 x 256.
// bid 0..255: ctx -> K,V. bid 256..511: x -> Q.
// Block: 64 pixels x 256 c. fp32 load -> LDS bf16 [p][c] -> MFMA GEMMs.
// Outputs in attn-ready fragment order (Pl / Vw wave-private re-swizzle).
// ---------------------------------------------------------------------------
__global__ __launch_bounds__(256, 2) void fused_proj(
        const float* __restrict__ x, const float* __restrict__ ctx,
        const uint4* __restrict__ Wqf, const uint4* __restrict__ Wkf,
        const uint4* __restrict__ Wvf,
        const float* __restrict__ bq, const float* __restrict__ bk,
        const float* __restrict__ bv,
        unsigned short* __restrict__ Qf, unsigned short* __restrict__ Kf,
        unsigned char* __restrict__ Vf) {
    __shared__ unsigned short X[64][264];      // 33792 B, [p][c], pad 8
    __shared__ unsigned short Pl[4][16 * 40];  // per-wave Q/K swizzle (5120 B)
    __shared__ unsigned char  Vw[4][16 * 40];  // per-wave V swizzle (2560 B)

    int bid = blockIdx.x;
    bool isX = bid >= 256;
    int lb = bid & 255;
    int b = lb >> 6, pt64 = lb & 63;
    const float* __restrict__ in = (isX ? x : ctx) + (size_t)b * C_ * N_ + pt64 * 64;
    int t = threadIdx.x, wg = t >> 6, lane = t & 63;
    int low = lane & 15, q = lane >> 4;

    // ---- transpose 64p x 256c into LDS bf16 ----
    {
        int pL = lane;
        const float* s0 = in + pL;
#pragma unroll
        for (int ct = 0; ct < 4; ct++) {
            const float* s2 = s0 + (size_t)(ct * 64 + wg * 16) * N_;
            float v[16];
#pragma unroll
            for (int k = 0; k < 16; k++) v[k] = s2[(size_t)k * N_];
#pragma unroll
            for (int k = 0; k < 16; k += 2)
                *(unsigned*)&X[pL][ct * 64 + wg * 16 + k] = bfpk(v[k], v[k + 1]);
        }
    }
    __syncthreads();

    // ---- Q or K projection: wave wg -> ptile wg (16 pixels) ----
    {
        const uint4* __restrict__ Wf = isX ? Wqf : Wkf;
        const float* __restrict__ bias = isX ? bq : bk;
        unsigned short* __restrict__ dst = isX ? Qf : Kf;
        bf16x8 xf[8];
#pragma unroll
        for (int ch = 0; ch < 8; ch++)
            xf[ch] = *(const bf16x8*)&X[wg * 16 + low][ch * 32 + q * 8];
        const f32x4 zero = {0.f, 0.f, 0.f, 0.f};
        f32x4 acc[2] = {zero, zero};
#pragma unroll
        for (int rt = 0; rt < 2; rt++)
#pragma unroll
            for (int ch = 0; ch < 8; ch++) {
                uint4 wv = Wf[(rt * 8 + ch) * 64 + lane];
                acc[rt] = __builtin_amdgcn_mfma_f32_16x16x32_bf16(
                    __builtin_bit_cast(bf16x8, wv), xf[ch], acc[rt], 0, 0, 0);
            }
        unsigned short* Pw = &Pl[wg][0];
#pragma unroll
        for (int rt = 0; rt < 2; rt++) {
            float b0 = bias[rt * 16 + q * 4 + 0], b1 = bias[rt * 16 + q * 4 + 1];
            float b2 = bias[rt * 16 + q * 4 + 2], b3 = bias[rt * 16 + q * 4 + 3];
            uint2 pk = {bfpk(acc[rt][0] + b0, acc[rt][1] + b1),
                        bfpk(acc[rt][2] + b2, acc[rt][3] + b3)};
            *(uint2*)(Pw + low * 40 + rt * 16 + q * 4) = pk;
        }
        uint4 frag = *(const uint4*)(Pw + low * 40 + q * 8);
        ((uint4*)dst)[((size_t)b * 256 + pt64 * 4 + wg) * 64 + lane] = frag;
    }

    // ---- V projection (ctx blocks only) ----
    if (!isX) {
        int mstep = wg >> 1, dh = wg & 1;   // wave: one 32-m step, 8 d-tiles
        bf16x8 vfr[2][8];
#pragma unroll
        for (int mt = 0; mt < 2; mt++)
#pragma unroll
            for (int ch = 0; ch < 8; ch++)
                vfr[mt][ch] = *(const bf16x8*)&X[mstep * 32 + mt * 16 + low][ch * 32 + q * 8];
        unsigned char* Vv = &Vw[wg][0];
        int msg = pt64 * 2 + mstep;
        const f32x4 zero = {0.f, 0.f, 0.f, 0.f};
#pragma unroll
        for (int dt8 = 0; dt8 < 8; dt8++) {
            int dt = dh * 8 + dt8;
            f32x4 a0 = zero, a1 = zero;
#pragma unroll
            for (int ch = 0; ch < 8; ch++) {
                uint4 wv = Wvf[(dt * 8 + ch) * 64 + lane];
                bf16x8 wfr = __builtin_bit_cast(bf16x8, wv);
                a0 = __builtin_amdgcn_mfma_f32_16x16x32_bf16(vfr[0][ch], wfr, a0, 0, 0, 0);
                a1 = __builtin_amdgcn_mfma_f32_16x16x32_bf16(vfr[1][ch], wfr, a1, 0, 0, 0);
            }
            float bb = bv[dt * 16 + low];
            unsigned w0 = __builtin_amdgcn_cvt_pk_fp8_f32(a0[0] + bb, a0[1] + bb, 0, false);
            w0 = __builtin_amdgcn_cvt_pk_fp8_f32(a0[2] + bb, a0[3] + bb, w0, true);
            unsigned w1 = __builtin_amdgcn_cvt_pk_fp8_f32(a1[0] + bb, a1[1] + bb, 0, false);
            w1 = __builtin_amdgcn_cvt_pk_fp8_f32(a1[2] + bb, a1[3] + bb, w1, true);
            *(unsigned*)(Vv + low * 40 + q * 4) = w0;
            *(unsigned*)(Vv + low * 40 + 16 + q * 4) = w1;
            uint2 fr = *(const uint2*)(Vv + low * 40 + q * 8);
            ((uint2*)Vf)[(((size_t)b * 128 + msg) * 16 + dt) * 64 + lane] = fr;
        }
    }
}

// ---------------------------------------------------------------------------
// Flash attention, split-m by 8. grid 2048, 256 thr, 4 blocks/CU.
// 1 q-tile/wave (acc = 64 VGPR). v4 iteration structure (no lag).
// ---------------------------------------------------------------------------
__global__ __launch_bounds__(256, 4) void attn(
        const unsigned short* __restrict__ Qf, const unsigned short* __restrict__ Kf,
        const unsigned char* __restrict__ Vf, unsigned char* __restrict__ Op,
        float* __restrict__ Lp) {
    __shared__ __align__(16) unsigned char vbuf[2][16384];
    __shared__ __align__(16) unsigned char Plds[4][16 * 72];

    int v = blockIdx.x & 31;
    int b = v >> 3, chunk = v & 7;
    int ntg = blockIdx.x >> 5;              // 0..63
    int wave = threadIdx.x >> 6, lane = threadIdx.x & 63;
    int quad = lane >> 4, col = lane & 15;
    int nt = ntg * 4 + wave;                // 0..255

    const uint4* Qp = (const uint4*)Qf;
    const uint4* Kp = (const uint4*)Kf + (size_t)b * 256 * 64;
    const unsigned char* Vp = Vf + (size_t)b * 1048576;

    bf16x8 qa = __builtin_bit_cast(bf16x8, Qp[(size_t)(b * 256 + nt) * 64 + lane]);

    f32x4 acc[16];
#pragma unroll
    for (int dt = 0; dt < 16; dt++) acc[dt] = (f32x4){0.f, 0.f, 0.f, 0.f};
    float lacc[4] = {0.f, 0.f, 0.f, 0.f};

    unsigned char* Pw = &Plds[wave][0];
    const f32x4 zero = {0.f, 0.f, 0.f, 0.f};
    int ms0 = chunk * 8;

    // prologue: stage first 16 KB V slab
#pragma unroll
    for (int ii = 0; ii < 4; ii++) {
        int ck = wave * 4 + ii;
        gload_lds16(Vp + (size_t)ms0 * 16384 + ck * 1024 + lane * 16,
                    &vbuf[0][0] + ck * 1024 + lane * 16);
    }
    uint4 kv[4];
#pragma unroll
    for (int u = 0; u < 4; u++)
        kv[u] = Kp[(size_t)(ms0 * 4 + u) * 64 + lane];

    int p = 0;
    for (int i = 0; i < 8; i++) {
        int ms = ms0 + i;
        __syncthreads();

        int msn = (i < 7) ? ms + 1 : ms;
#pragma unroll
        for (int ii = 0; ii < 4; ii++) {
            int ck = wave * 4 + ii;
            gload_lds16(Vp + (size_t)msn * 16384 + ck * 1024 + lane * 16,
                        &vbuf[p ^ 1][0] + ck * 1024 + lane * 16);
        }

        // S = Q K^T (4 MFMAs)
        f32x4 s[4];
#pragma unroll
        for (int u = 0; u < 4; u++)
            s[u] = __builtin_amdgcn_mfma_f32_16x16x32_bf16(
                qa, __builtin_bit_cast(bf16x8, kv[u]), zero, 0, 0, 0);

        // prefetch K(i+1)
#pragma unroll
        for (int u = 0; u < 4; u++)
            kv[u] = Kp[(size_t)(msn * 4 + u) * 64 + lane];

        // exp / P (fp8) via wave-private LDS
#pragma unroll
        for (int u = 0; u < 4; u++) {
#pragma unroll
            for (int r = 0; r < 4; r++) {
                float pe = __expf(s[u][r] * SCALE_);
                lacc[r] += pe;
                unsigned w8 = __builtin_amdgcn_cvt_pk_fp8_f32(pe, pe, 0, false);
                Pw[(quad * 4 + r) * 72 + u * 16 + col] = (unsigned char)w8;
            }
        }
        unsigned long long pa0 = *(const unsigned long long*)(Pw + col * 72 + quad * 8);
        unsigned long long pa1 = *(const unsigned long long*)(Pw + col * 72 + 32 + quad * 8);

        // O += P V' (32 MFMAs, V from LDS)
        const unsigned char* vb = &vbuf[p][0];
#pragma unroll
        for (int dt = 0; dt < 16; dt++) {
            long v0 = *(const long*)(vb + (size_t)dt * 512 + lane * 8);
            long v1 = *(const long*)(vb + (size_t)(16 + dt) * 512 + lane * 8);
            acc[dt] = __builtin_amdgcn_mfma_f32_16x16x32_fp8_fp8(
                (long)pa0, v0, acc[dt], 0, 0, 0);
            acc[dt] = __builtin_amdgcn_mfma_f32_16x16x32_fp8_fp8(
                (long)pa1, v1, acc[dt], 0, 0, 0);
        }
        p ^= 1;
    }

#pragma unroll
    for (int off = 1; off <= 8; off <<= 1) {
#pragma unroll
        for (int r = 0; r < 4; r++) lacc[r] += __shfl_xor(lacc[r], off, 64);
    }
    int tileg = b * 256 + nt;
    if (col == 0) {
#pragma unroll
        for (int r = 0; r < 4; r++)
            Lp[((size_t)tileg * 8 + chunk) * 16 + quad * 4 + r] = lacc[r];
    }
#pragma unroll
    for (int dt = 0; dt < 16; dt++) {
        int d = dt * 16 + col;
        size_t sb = ((size_t)(b * 8 + chunk) * C_ + d) * N_ + nt * 16 + quad * 4;
        unsigned w = __builtin_amdgcn_cvt_pk_fp8_f32(acc[dt][0], acc[dt][1], 0, false);
        w = __builtin_amdgcn_cvt_pk_fp8_f32(acc[dt][2], acc[dt][3], w, true);
        *(unsigned*)(Op + sb) = w;
    }
}

// ---------------------------------------------------------------------------
// Combine: out = gamma * (sum_c O_c) / (sum_c l_c) + x. HBM-bound.
// ---------------------------------------------------------------------------
__global__ __launch_bounds__(256) void combine(
        const unsigned char* __restrict__ Op, const float* __restrict__ Lp,
        const float* __restrict__ x, const float* __restrict__ gamma,
        float* __restrict__ out) {
    int idx = blockIdx.x * 256 + threadIdx.x;
    int n4 = idx & 1023;
    int d = (idx >> 10) & 255;
    int b = idx >> 18;
    int n = n4 * 4;
    int tile = b * 256 + (n >> 4);
    int row0 = n & 15;

    float o[4] = {0.f, 0.f, 0.f, 0.f};
    f32x4 l = {0.f, 0.f, 0.f, 0.f};
#pragma unroll
    for (int c = 0; c < 8; c++) {
        size_t sb = ((size_t)(b * 8 + c) * C_ + d) * N_ + n;
        unsigned pv = *(const unsigned*)(Op + sb);
        o[0] += fp8d(pv & 0xffu);
        o[1] += fp8d((pv >> 8) & 0xffu);
        o[2] += fp8d((pv >> 16) & 0xffu);
        o[3] += fp8d(pv >> 24);
        f32x4 lv = *(const f32x4*)&Lp[((size_t)tile * 8 + c) * 16 + row0];
        l += lv;
    }
    float g = gamma[0];
    size_t ob = ((size_t)b * C_ + d) * N_ + n;
    f32x4 xv = *(const f32x4*)(x + ob);
    f32x4 res;
#pragma unroll
    for (int r = 0; r < 4; r++) res[r] = g * o[r] / l[r] + xv[r];
    *(f32x4*)(out + ob) = res;
}

// ---------------------------------------------------------------------------
extern "C" void kernel_launch(void* const* d_in, const int* in_sizes, int n_in,
                              void* d_out, int out_size, void* d_ws, size_t ws_size,
                              hipStream_t stream) {
    const float* x     = (const float*)d_in[0];
    const float* ctx   = (const float*)d_in[1];
    const float* Wq    = (const float*)d_in[2];
    const float* bq    = (const float*)d_in[3];
    const float* Wk    = (const float*)d_in[4];
    const float* bk    = (const float*)d_in[5];
    const float* Wv    = (const float*)d_in[6];
    const float* bv    = (const float*)d_in[7];
    const float* gamma = (const float*)d_in[8];
    float* out = (float*)d_out;

    // ws: Qf 1M | Kf 1M | Vf 4.2M | Wqf 16K | Wkf 16K | Wvf 128K | Op 33.6M | Lp 0.5M
    unsigned short* Qf = (unsigned short*)d_ws;
    unsigned short* Kf = Qf + (size_t)B_ * N_ * 32;
    unsigned char*  Vf = (unsigned char*)(Kf + (size_t)B_ * M_ * 32);
    uint4* Wqf = (uint4*)(Vf + (size_t)B_ * M_ * C_);
    uint4* Wkf = Wqf + 16 * 64;
    uint4* Wvf = Wkf + 16 * 64;
    unsigned char* Op = (unsigned char*)(Wvf + 128 * 64);
    float* Lp = (float*)(Op + (size_t)B_ * 8 * C_ * N_);

    prep<<<40, 256, 0, stream>>>(Wq, Wk, Wv, Wqf, Wkf, Wvf);
    fused_proj<<<512, 256, 0, stream>>>(x, ctx, Wqf, Wkf, Wvf, bq, bk, bv, Qf, Kf, Vf);
    attn<<<2048, 256, 0, stream>>>(Qf, Kf, Vf, Op, Lp);
    combine<<<4096, 256, 0, stream>>>(Op, Lp, x, gamma, out);
}

// Round 7
// 151.174 us; speedup vs baseline: 1.3008x; 1.1673x over previous
//
#include <hip/hip_runtime.h>
#include <hip/hip_bf16.h>

// CrossAttention: B=4, C=256, H=W=64 -> N=M=4096, RC=32
// v7: attn restructured: S^T via operand swap (A/B frag layouts identical),
//     P packed as dwords; d-split across waves (V reads /4, acc regs /2,
//     3 blocks/CU); PV computes O^T; one barrier/iter; O transposed once per
//     block. Op = 3 fp8 partials in [n][d] layout; combine transposes via LDS.

#define B_ 4
#define C_ 256
#define N_ 4096
#define M_ 4096
#define SCALE_ 0.17677669529663687f  // 1/sqrt(32)

typedef __bf16 bf16x8 __attribute__((ext_vector_type(8)));
typedef float f32x4 __attribute__((ext_vector_type(4)));

#define AS1 __attribute__((address_space(1)))
#define AS3 __attribute__((address_space(3)))

static __device__ __forceinline__ unsigned short f2bf(float f) {
    unsigned int u = __float_as_uint(f);
    return (unsigned short)((u + 0x7fffu + ((u >> 16) & 1u)) >> 16);
}
static __device__ __forceinline__ unsigned bfpk(float a, float b) {
    return (unsigned)f2bf(a) | ((unsigned)f2bf(b) << 16);
}
static __device__ __forceinline__ float fp8d(unsigned v) {  // e4m3fn decode
    unsigned e = (v >> 3) & 15, m = v & 7;
    float f = e ? __uint_as_float(((e + 120u) << 23) | (m << 20))
                : (float)m * 0x1p-9f;
    return (v & 0x80u) ? -f : f;
}
static __device__ __forceinline__ void gload_lds16(const void* g, void* l) {
    __builtin_amdgcn_global_load_lds((const AS1 unsigned int*)g,
                                     (AS3 unsigned int*)l, 16, 0, 0);
}

// ---------------------------------------------------------------------------
// prep: weights -> bf16 MFMA fragment order. grid 40 x 256. (unchanged)
// ---------------------------------------------------------------------------
__global__ __launch_bounds__(256) void prep(
        const float* __restrict__ Wq, const float* __restrict__ Wk,
        const float* __restrict__ Wv, uint4* __restrict__ Wqf,
        uint4* __restrict__ Wkf, uint4* __restrict__ Wvf) {
    int bid = blockIdx.x, t = threadIdx.x;
    const float* W;
    uint4* dst;
    int frag;
    if (bid < 32)      { W = Wv; dst = Wvf; frag = (bid * 256 + t) >> 6; }
    else if (bid < 36) { W = Wq; dst = Wqf; frag = ((bid - 32) * 256 + t) >> 6; }
    else               { W = Wk; dst = Wkf; frag = ((bid - 36) * 256 + t) >> 6; }
    int lane = t & 63, low = lane & 15, q = lane >> 4;
    int fch = frag & 7, fr = frag >> 3;
    const float* wp = W + (size_t)(fr * 16 + low) * C_ + fch * 32 + q * 8;
    float4 w0 = *(const float4*)wp;
    float4 w1 = *(const float4*)(wp + 4);
    uint4 pk = {bfpk(w0.x, w0.y), bfpk(w0.z, w0.w),
                bfpk(w1.x, w1.y), bfpk(w1.z, w1.w)};
    dst[(size_t)frag * 64 + lane] = pk;
}

// ---------------------------------------------------------------------------
// Fused transpose + projections. grid 512 x 256. (unchanged from v6)
// ---------------------------------------------------------------------------
__global__ __launch_bounds__(256, 2) void fused_proj(
        const float* __restrict__ x, const float* __restrict__ ctx,
        const uint4* __restrict__ Wqf, const uint4* __restrict__ Wkf,
        const uint4* __restrict__ Wvf,
        const float* __restrict__ bq, const float* __restrict__ bk,
        const float* __restrict__ bv,
        unsigned short* __restrict__ Qf, unsigned short* __restrict__ Kf,
        unsigned char* __restrict__ Vf) {
    __shared__ unsigned short X[64][264];
    __shared__ unsigned short Pl[4][16 * 40];
    __shared__ unsigned char  Vw[4][16 * 40];

    int bid = blockIdx.x;
    bool isX = bid >= 256;
    int lb = bid & 255;
    int b = lb >> 6, pt64 = lb & 63;
    const float* __restrict__ in = (isX ? x : ctx) + (size_t)b * C_ * N_ + pt64 * 64;
    int t = threadIdx.x, wg = t >> 6, lane = t & 63;
    int low = lane & 15, q = lane >> 4;

    {
        int pL = lane;
        const float* s0 = in + pL;
#pragma unroll
        for (int ct = 0; ct < 4; ct++) {
            const float* s2 = s0 + (size_t)(ct * 64 + wg * 16) * N_;
            float v[16];
#pragma unroll
            for (int k = 0; k < 16; k++) v[k] = s2[(size_t)k * N_];
#pragma unroll
            for (int k = 0; k < 16; k += 2)
                *(unsigned*)&X[pL][ct * 64 + wg * 16 + k] = bfpk(v[k], v[k + 1]);
        }
    }
    __syncthreads();

    {
        const uint4* __restrict__ Wf = isX ? Wqf : Wkf;
        const float* __restrict__ bias = isX ? bq : bk;
        unsigned short* __restrict__ dst = isX ? Qf : Kf;
        bf16x8 xf[8];
#pragma unroll
        for (int ch = 0; ch < 8; ch++)
            xf[ch] = *(const bf16x8*)&X[wg * 16 + low][ch * 32 + q * 8];
        const f32x4 zero = {0.f, 0.f, 0.f, 0.f};
        f32x4 acc[2] = {zero, zero};
#pragma unroll
        for (int rt = 0; rt < 2; rt++)
#pragma unroll
            for (int ch = 0; ch < 8; ch++) {
                uint4 wv = Wf[(rt * 8 + ch) * 64 + lane];
                acc[rt] = __builtin_amdgcn_mfma_f32_16x16x32_bf16(
                    __builtin_bit_cast(bf16x8, wv), xf[ch], acc[rt], 0, 0, 0);
            }
        unsigned short* Pw = &Pl[wg][0];
#pragma unroll
        for (int rt = 0; rt < 2; rt++) {
            float b0 = bias[rt * 16 + q * 4 + 0], b1 = bias[rt * 16 + q * 4 + 1];
            float b2 = bias[rt * 16 + q * 4 + 2], b3 = bias[rt * 16 + q * 4 + 3];
            uint2 pk = {bfpk(acc[rt][0] + b0, acc[rt][1] + b1),
                        bfpk(acc[rt][2] + b2, acc[rt][3] + b3)};
            *(uint2*)(Pw + low * 40 + rt * 16 + q * 4) = pk;
        }
        uint4 frag = *(const uint4*)(Pw + low * 40 + q * 8);
        ((uint4*)dst)[((size_t)b * 256 + pt64 * 4 + wg) * 64 + lane] = frag;
    }

    if (!isX) {
        int mstep = wg >> 1, dh = wg & 1;
        bf16x8 vfr[2][8];
#pragma unroll
        for (int mt = 0; mt < 2; mt++)
#pragma unroll
            for (int ch = 0; ch < 8; ch++)
                vfr[mt][ch] = *(const bf16x8*)&X[mstep * 32 + mt * 16 + low][ch * 32 + q * 8];
        unsigned char* Vv = &Vw[wg][0];
        int msg = pt64 * 2 + mstep;
        const f32x4 zero = {0.f, 0.f, 0.f, 0.f};
#pragma unroll
        for (int dt8 = 0; dt8 < 8; dt8++) {
            int dt = dh * 8 + dt8;
            f32x4 a0 = zero, a1 = zero;
#pragma unroll
            for (int ch = 0; ch < 8; ch++) {
                uint4 wv = Wvf[(dt * 8 + ch) * 64 + lane];
                bf16x8 wfr = __builtin_bit_cast(bf16x8, wv);
                a0 = __builtin_amdgcn_mfma_f32_16x16x32_bf16(vfr[0][ch], wfr, a0, 0, 0, 0);
                a1 = __builtin_amdgcn_mfma_f32_16x16x32_bf16(vfr[1][ch], wfr, a1, 0, 0, 0);
            }
            float bb = bv[dt * 16 + low];
            unsigned w0 = __builtin_amdgcn_cvt_pk_fp8_f32(a0[0] + bb, a0[1] + bb, 0, false);
            w0 = __builtin_amdgcn_cvt_pk_fp8_f32(a0[2] + bb, a0[3] + bb, w0, true);
            unsigned w1 = __builtin_amdgcn_cvt_pk_fp8_f32(a1[0] + bb, a1[1] + bb, 0, false);
            w1 = __builtin_amdgcn_cvt_pk_fp8_f32(a1[2] + bb, a1[3] + bb, w1, true);
            *(unsigned*)(Vv + low * 40 + q * 4) = w0;
            *(unsigned*)(Vv + low * 40 + 16 + q * 4) = w1;
            uint2 fr = *(const uint2*)(Vv + low * 40 + q * 8);
            ((uint2*)Vf)[(((size_t)b * 128 + msg) * 16 + dt) * 64 + lane] = fr;
        }
    }
}

// ---------------------------------------------------------------------------
// Flash attention v7. grid 768 (= 3 blocks/CU), 256 thr (4 waves).
// bid = (b*3+chunk)*64 + ng. Block: 4 q-tiles (64 n), m-chunk of ~1400.
// Wave w: S^T/softmax for tile w; PV for ALL tiles restricted to d-tiles
// [4w,4w+4). P (fp8, [n][m]) shared via LDS ping-pong; V slabs (64 m, 16 KB)
// DMA double-buffered. PV(i) overlaps S/softmax(i+1). O^T -> LDS transpose
// once per block -> Op fp8 in [n][d] layout.
// ---------------------------------------------------------------------------
__global__ __launch_bounds__(256, 3) void attn(
        const unsigned short* __restrict__ Qf, const unsigned short* __restrict__ Kf,
        const unsigned char* __restrict__ Vf, unsigned char* __restrict__ Op,
        float* __restrict__ Lp) {
    __shared__ __align__(16) unsigned char vbuf[2][16384];   // 32 KB
    __shared__ __align__(16) unsigned char Pb[2][4][16 * 72]; // 9216 B

    int bid = blockIdx.x;
    int v = bid >> 6;                 // b*3 + chunk (0..11)
    int ng = bid & 63;
    int b = v / 3;
    int chunk = v - b * 3;
    int I  = (chunk == 0) ? 22 : 21;  // 22+21+21 = 64 slabs of 64 m
    int s0 = (chunk == 0) ? 0 : (chunk == 1 ? 22 : 43);

    int wave = threadIdx.x >> 6, lane = threadIdx.x & 63;
    int q = lane >> 4, low = lane & 15;
    int nt = ng * 4 + wave;           // wave's own q-tile (0..255)

    const uint4* Qp = (const uint4*)Qf;
    const uint4* Kp = (const uint4*)Kf + (size_t)b * 256 * 64;
    const unsigned char* Vp = Vf + (size_t)b * 1048576;

    bf16x8 qa = __builtin_bit_cast(bf16x8, Qp[(size_t)(b * 256 + nt) * 64 + lane]);

    f32x4 acc[4][4];                  // [tile][d-tile-local]: O^T
#pragma unroll
    for (int tt = 0; tt < 4; tt++)
#pragma unroll
        for (int dd = 0; dd < 4; dd++) acc[tt][dd] = (f32x4){0.f, 0.f, 0.f, 0.f};
    float lacc = 0.f;
    const f32x4 zero = {0.f, 0.f, 0.f, 0.f};

    // ---- prologue: S^T(0), P(0), DMA V(0), prefetch K(1) ----
    uint4 kv[4];
#pragma unroll
    for (int u = 0; u < 4; u++)
        kv[u] = Kp[(size_t)(s0 * 4 + u) * 64 + lane];
    f32x4 s[4];
#pragma unroll
    for (int u = 0; u < 4; u++)
        s[u] = __builtin_amdgcn_mfma_f32_16x16x32_bf16(
            __builtin_bit_cast(bf16x8, kv[u]), qa, zero, 0, 0, 0);
#pragma unroll
    for (int ii = 0; ii < 4; ii++) {
        int ck = wave * 4 + ii;
        gload_lds16(Vp + (size_t)s0 * 16384 + ck * 1024 + lane * 16,
                    &vbuf[0][0] + ck * 1024 + lane * 16);
    }
    if (I > 1) {
#pragma unroll
        for (int u = 0; u < 4; u++)
            kv[u] = Kp[(size_t)((s0 + 1) * 4 + u) * 64 + lane];
    }
    {
        unsigned char* Pw = &Pb[0][wave][0];
#pragma unroll
        for (int u = 0; u < 4; u++) {
            float p0 = __expf(s[u][0] * SCALE_), p1 = __expf(s[u][1] * SCALE_);
            float p2 = __expf(s[u][2] * SCALE_), p3 = __expf(s[u][3] * SCALE_);
            lacc += p0 + p1 + p2 + p3;
            unsigned w = __builtin_amdgcn_cvt_pk_fp8_f32(p0, p1, 0, false);
            w = __builtin_amdgcn_cvt_pk_fp8_f32(p2, p3, w, true);
            *(unsigned*)(Pw + low * 72 + u * 16 + q * 4) = w;
        }
    }
    __syncthreads();

    // ---- main loop ----
    for (int i = 0; i < I; i++) {
        int cur = i & 1, nxt = cur ^ 1;
        if (i + 1 < I) {
#pragma unroll
            for (int ii = 0; ii < 4; ii++) {
                int ck = wave * 4 + ii;
                gload_lds16(Vp + (size_t)(s0 + i + 1) * 16384 + ck * 1024 + lane * 16,
                            &vbuf[nxt][0] + ck * 1024 + lane * 16);
            }
#pragma unroll
            for (int u = 0; u < 4; u++)
                s[u] = __builtin_amdgcn_mfma_f32_16x16x32_bf16(
                    __builtin_bit_cast(bf16x8, kv[u]), qa, zero, 0, 0, 0);
            if (i + 2 < I) {
#pragma unroll
                for (int u = 0; u < 4; u++)
                    kv[u] = Kp[(size_t)((s0 + i + 2) * 4 + u) * 64 + lane];
            }
        }

        // ---- PV(i): O^T[tile][wave's d-tiles] += V^T P^T ----
        const unsigned char* vb = &vbuf[cur][0];
        const unsigned char* Pr = &Pb[cur][0][0];
        long pfr[4][2];
#pragma unroll
        for (int tt = 0; tt < 4; tt++) {
            pfr[tt][0] = *(const long*)(Pr + tt * 1152 + low * 72 + q * 8);
            pfr[tt][1] = *(const long*)(Pr + tt * 1152 + low * 72 + 32 + q * 8);
        }
        long vfr[4][2];
#pragma unroll
        for (int dd = 0; dd < 4; dd++) {
            int dt = wave * 4 + dd;
            vfr[dd][0] = *(const long*)(vb + dt * 512 + lane * 8);
            vfr[dd][1] = *(const long*)(vb + 8192 + dt * 512 + lane * 8);
        }
#pragma unroll
        for (int tt = 0; tt < 4; tt++)
#pragma unroll
            for (int dd = 0; dd < 4; dd++) {
                acc[tt][dd] = __builtin_amdgcn_mfma_f32_16x16x32_fp8_fp8(
                    vfr[dd][0], pfr[tt][0], acc[tt][dd], 0, 0, 0);
                acc[tt][dd] = __builtin_amdgcn_mfma_f32_16x16x32_fp8_fp8(
                    vfr[dd][1], pfr[tt][1], acc[tt][dd], 0, 0, 0);
            }

        if (i + 1 < I) {
            unsigned char* Pw = &Pb[nxt][wave][0];
#pragma unroll
            for (int u = 0; u < 4; u++) {
                float p0 = __expf(s[u][0] * SCALE_), p1 = __expf(s[u][1] * SCALE_);
                float p2 = __expf(s[u][2] * SCALE_), p3 = __expf(s[u][3] * SCALE_);
                lacc += p0 + p1 + p2 + p3;
                unsigned w = __builtin_amdgcn_cvt_pk_fp8_f32(p0, p1, 0, false);
                w = __builtin_amdgcn_cvt_pk_fp8_f32(p2, p3, w, true);
                *(unsigned*)(Pw + low * 72 + u * 16 + q * 4) = w;
            }
        }
        __syncthreads();
    }

    // ---- l: reduce across quads (m-partials), store per n ----
    lacc += __shfl_xor(lacc, 16, 64);
    lacc += __shfl_xor(lacc, 32, 64);
    if (lane < 16)
        Lp[(size_t)v * 4096 + nt * 16 + lane] = lacc;

    // ---- O^T -> [n][d] fp8 via LDS (once per block) ----
    unsigned* Odw = (unsigned*)&vbuf[0][0];  // 64 rows x 68 dwords (17.4 KB)
#pragma unroll
    for (int tt = 0; tt < 4; tt++)
#pragma unroll
        for (int dd = 0; dd < 4; dd++) {
            unsigned w = __builtin_amdgcn_cvt_pk_fp8_f32(acc[tt][dd][0], acc[tt][dd][1], 0, false);
            w = __builtin_amdgcn_cvt_pk_fp8_f32(acc[tt][dd][2], acc[tt][dd][3], w, true);
            Odw[(tt * 16 + low) * 68 + wave * 16 + dd * 4 + q] = w;
        }
    __syncthreads();
    {
        int n = threadIdx.x >> 2, c4 = threadIdx.x & 3;
        size_t rb = ((size_t)v * 4096 + ng * 64 + n) * 256;
#pragma unroll
        for (int k = 0; k < 4; k++)
            *(uint4*)(Op + rb + c4 * 64 + k * 16) =
                *(const uint4*)&Odw[n * 68 + c4 * 16 + k * 4];
    }
}

// ---------------------------------------------------------------------------
// Combine: out = gamma * (sum_p O_p) / (sum_p l_p) + x.
// Op is [partial][n][d] fp8 -> LDS transpose to write out[d][n]. grid 512.
// ---------------------------------------------------------------------------
__global__ __launch_bounds__(256) void combine(
        const unsigned char* __restrict__ Op, const float* __restrict__ Lp,
        const float* __restrict__ x, const float* __restrict__ gamma,
        float* __restrict__ out) {
    __shared__ float W[32][260];
    int bid = blockIdx.x;
    int b = bid >> 7, n0 = (bid & 127) * 32;
    int t = threadIdx.x;
    float g = gamma[0];
    {
        int d4 = t & 63, nn = t >> 6;
#pragma unroll
        for (int rr = 0; rr < 8; rr++) {
            int n = rr * 4 + nn;
            float o0 = 0.f, o1 = 0.f, o2 = 0.f, o3 = 0.f, l = 0.f;
#pragma unroll
            for (int p = 0; p < 3; p++) {
                size_t base = (size_t)(b * 3 + p) * 4096 + n0 + n;
                unsigned pv = *(const unsigned*)(Op + base * 256 + d4 * 4);
                o0 += fp8d(pv & 255u); o1 += fp8d((pv >> 8) & 255u);
                o2 += fp8d((pv >> 16) & 255u); o3 += fp8d(pv >> 24);
                l += Lp[base];
            }
            float sc = g / l;
            f32x4 w = {o0 * sc, o1 * sc, o2 * sc, o3 * sc};
            *(f32x4*)&W[n][d4 * 4] = w;
        }
    }
    __syncthreads();
    {
        int d = t;
        size_t rb = ((size_t)b * 256 + d) * 4096 + n0;
#pragma unroll
        for (int k = 0; k < 8; k++) {
            f32x4 xv = *(const f32x4*)(x + rb + k * 4);
            f32x4 res;
#pragma unroll
            for (int r = 0; r < 4; r++) res[r] = W[k * 4 + r][d] + xv[r];
            *(f32x4*)(out + rb + k * 4) = res;
        }
    }
}

// ---------------------------------------------------------------------------
extern "C" void kernel_launch(void* const* d_in, const int* in_sizes, int n_in,
                              void* d_out, int out_size, void* d_ws, size_t ws_size,
                              hipStream_t stream) {
    const float* x     = (const float*)d_in[0];
    const float* ctx   = (const float*)d_in[1];
    const float* Wq    = (const float*)d_in[2];
    const float* bq    = (const float*)d_in[3];
    const float* Wk    = (const float*)d_in[4];
    const float* bk    = (const float*)d_in[5];
    const float* Wv    = (const float*)d_in[6];
    const float* bv    = (const float*)d_in[7];
    const float* gamma = (const float*)d_in[8];
    float* out = (float*)d_out;

    // ws: Qf 1M | Kf 1M | Vf 4.2M | Wqf/Wkf 16K | Wvf 128K | Op 12.6M | Lp 196K
    unsigned short* Qf = (unsigned short*)d_ws;
    unsigned short* Kf = Qf + (size_t)B_ * N_ * 32;
    unsigned char*  Vf = (unsigned char*)(Kf + (size_t)B_ * M_ * 32);
    uint4* Wqf = (uint4*)(Vf + (size_t)B_ * M_ * C_);
    uint4* Wkf = Wqf + 16 * 64;
    uint4* Wvf = Wkf + 16 * 64;
    unsigned char* Op = (unsigned char*)(Wvf + 128 * 64);
    float* Lp = (float*)(Op + (size_t)3 * B_ * N_ * C_);

    prep<<<40, 256, 0, stream>>>(Wq, Wk, Wv, Wqf, Wkf, Wvf);
    fused_proj<<<512, 256, 0, stream>>>(x, ctx, Wqf, Wkf, Wvf, bq, bk, bv, Qf, Kf, Vf);
    attn<<<768, 256, 0, stream>>>(Qf, Kf, Vf, Op, Lp);
    combine<<<512, 256, 0, stream>>>(Op, Lp, x, gamma, out);
}